// Round 1
// 177.038 us; speedup vs baseline: 1.0121x; 1.0121x over previous
//
#include <hip/hip_runtime.h>
#include <hip/hip_bf16.h>

// Problem constants
static constexpr int Bc = 4;
static constexpr int Lc = 2048;
static constexpr int Cc = 512;     // FEATURE_DIM
static constexpr int Hc = 8;       // NUM_HEADS
static constexpr int Dc = 64;      // HEAD_DIM

using short8  = __attribute__((ext_vector_type(8))) short;
using float4v = __attribute__((ext_vector_type(4))) float;
using f32x16  = __attribute__((ext_vector_type(16))) float;

static __device__ __forceinline__ unsigned short f2bf(float f) {
    __hip_bfloat16 h = __float2bfloat16(f);   // RNE
    return *reinterpret_cast<unsigned short*>(&h);
}
static __device__ __forceinline__ float bf2f(unsigned short u) {
    return __uint_as_float(((unsigned int)u) << 16);
}

// async global->LDS, 16B per lane; lptr must be wave-uniform (HW scatters lane*16)
static __device__ __forceinline__ void gll16(const unsigned short* g, unsigned short* l) {
    __builtin_amdgcn_global_load_lds(
        (const __attribute__((address_space(1))) unsigned int*)g,
        (__attribute__((address_space(3))) unsigned int*)l,
        16, 0, 0);
}

// ---------------------------------------------------------------------------
// Kernel 0: prep (unchanged).
// ---------------------------------------------------------------------------
__global__ __launch_bounds__(256) void prep_kernel(
    const float* __restrict__ ppg, const float* __restrict__ ecg,
    const float* __restrict__ Wq, const float* __restrict__ Wk,
    const float* __restrict__ Wv, const float* __restrict__ Wo,
    unsigned short* __restrict__ Xt_ppg, unsigned short* __restrict__ Xt_ecg,
    unsigned short* __restrict__ Wbf)
{
    __shared__ float Ts[64 * 69];
    const int task = blockIdx.x;
    const int tid  = threadIdx.x;

    if (task < 2048) {
        const int src = task >> 10;
        const int rem = task & 1023;
        const int b   = rem >> 8;
        const int c0  = ((rem >> 5) & 7) * 64;
        const int l0  = (rem & 31) * 64;
        const float* X = src ? ecg : ppg;
        unsigned short* Xt = src ? Xt_ecg : Xt_ppg;

        #pragma unroll
        for (int j = 0; j < 4; ++j) {
            int idx = tid + j * 256;
            int c = idx >> 4, l4 = idx & 15;
            float4 v = *(const float4*)(X + ((size_t)b * Cc + c0 + c) * Lc + l0 + l4 * 4);
            Ts[c * 69 + l4 * 4 + 0] = v.x;
            Ts[c * 69 + l4 * 4 + 1] = v.y;
            Ts[c * 69 + l4 * 4 + 2] = v.z;
            Ts[c * 69 + l4 * 4 + 3] = v.w;
        }
        __syncthreads();
        #pragma unroll
        for (int j = 0; j < 8; ++j) {
            int u = tid + j * 256;
            int l = u >> 5, p2 = u & 31;
            float a = Ts[(2 * p2) * 69 + l];
            float bb = Ts[(2 * p2 + 1) * 69 + l];
            ushort2 pk; pk.x = f2bf(a); pk.y = f2bf(bb);
            *(ushort2*)(Xt + ((size_t)b * Lc + l0 + l) * Cc + c0 + 2 * p2) = pk;
        }
    } else {
        const int wb   = task - 2048;
        const int widx = wb >> 7;
        const float* W = widx == 0 ? Wq : widx == 1 ? Wk : widx == 2 ? Wv : Wo;
        size_t off = (size_t)(wb & 127) * 2048 + (size_t)tid * 8;
        float4 v0 = *(const float4*)(W + off);
        float4 v1 = *(const float4*)(W + off + 4);
        unsigned short pk[8] = {f2bf(v0.x), f2bf(v0.y), f2bf(v0.z), f2bf(v0.w),
                                f2bf(v1.x), f2bf(v1.y), f2bf(v1.z), f2bf(v1.w)};
        *(short8*)(Wbf + (size_t)widx * Cc * Cc + off) = *(const short8*)pk;
    }
}

// ---------------------------------------------------------------------------
// Kernel 1: Q/K/V projections (unchanged).
// ---------------------------------------------------------------------------
__global__ __launch_bounds__(256) void proj_kernel(
    const unsigned short* __restrict__ Xt_ppg,
    const unsigned short* __restrict__ Xt_ecg,
    const unsigned short* __restrict__ Wbf,
    const float* __restrict__ bq, const float* __restrict__ bk,
    const float* __restrict__ bv,
    unsigned short* __restrict__ Qw, unsigned short* __restrict__ Kw,
    unsigned short* __restrict__ Vtw)
{
    constexpr int LDW = 72;
    const int z = blockIdx.z, p = z >> 2, b = z & 3;
    const int l0 = blockIdx.x * 128, n0 = blockIdx.y * 128;
    const unsigned short* X = (p == 0) ? Xt_ppg : Xt_ecg;
    const unsigned short* W = Wbf + (size_t)p * Cc * Cc;
    const float* bias = (p == 0) ? bq : (p == 1) ? bk : bv;

    const int tid = threadIdx.x, wave = tid >> 6, lane = tid & 63;
    const int l16 = lane & 15, quad = lane >> 4;
    const int wr = wave >> 1, wc = wave & 1;

    __shared__ __align__(16) unsigned short At[128 * LDW];
    __shared__ __align__(16) unsigned short Bt[128 * LDW];

    float4v acc[4][4] = {};
    short8 areg[4], breg[4];

    const int srow = tid >> 3, sc8 = tid & 7;
    #pragma unroll
    for (int j = 0; j < 4; ++j) {
        areg[j] = *(const short8*)(X + ((size_t)b * Lc + l0 + srow + j * 32) * Cc + sc8 * 8);
        breg[j] = *(const short8*)(W + (size_t)(n0 + srow + j * 32) * Cc + sc8 * 8);
    }

    for (int c0 = 0; c0 < Cc; c0 += 64) {
        #pragma unroll
        for (int j = 0; j < 4; ++j) {
            *(short8*)&At[(srow + j * 32) * LDW + sc8 * 8] = areg[j];
            *(short8*)&Bt[(srow + j * 32) * LDW + sc8 * 8] = breg[j];
        }
        __syncthreads();

        if (c0 + 64 < Cc) {
            #pragma unroll
            for (int j = 0; j < 4; ++j) {
                areg[j] = *(const short8*)(X + ((size_t)b * Lc + l0 + srow + j * 32) * Cc
                                           + c0 + 64 + sc8 * 8);
                breg[j] = *(const short8*)(W + (size_t)(n0 + srow + j * 32) * Cc
                                           + c0 + 64 + sc8 * 8);
            }
        }

        const unsigned short* Am = (p < 2) ? At : Bt;
        const unsigned short* Bm = (p < 2) ? Bt : At;

        #pragma unroll
        for (int ks = 0; ks < 2; ++ks) {
            short8 bf[4];
            #pragma unroll
            for (int nt = 0; nt < 4; ++nt)
                bf[nt] = *(const short8*)&Bm[(wc * 64 + nt * 16 + l16) * LDW
                                             + ks * 32 + quad * 8];
            #pragma unroll
            for (int mt = 0; mt < 4; ++mt) {
                short8 af = *(const short8*)&Am[(wr * 64 + mt * 16 + l16) * LDW
                                                + ks * 32 + quad * 8];
                #pragma unroll
                for (int nt = 0; nt < 4; ++nt)
                    acc[mt][nt] = __builtin_amdgcn_mfma_f32_16x16x32_bf16(
                        af, bf[nt], acc[mt][nt], 0, 0, 0);
            }
        }
        __syncthreads();
    }

    if (p < 2) {
        const float sc = (p == 0) ? 0.18033688011112042f : 1.0f;  // 0.125*log2(e)
        unsigned short* dst = (p == 0) ? Qw : Kw;
        #pragma unroll
        for (int nt = 0; nt < 4; ++nt) {
            int n = n0 + wc * 64 + nt * 16 + l16;
            int h = n >> 6, d = n & 63;
            int bh = b * Hc + h;
            float bia = bias[n];
            #pragma unroll
            for (int mt = 0; mt < 4; ++mt) {
                #pragma unroll
                for (int r = 0; r < 4; ++r) {
                    int l = l0 + wr * 64 + mt * 16 + quad * 4 + r;
                    dst[((size_t)bh * Lc + l) * Dc + d] =
                        f2bf((acc[mt][nt][r] + bia) * sc);
                }
            }
        }
    } else {
        #pragma unroll
        for (int mt = 0; mt < 4; ++mt) {
            #pragma unroll
            for (int r = 0; r < 4; ++r) {
                int n = n0 + wr * 64 + mt * 16 + quad * 4 + r;
                int h = n >> 6, d = n & 63;
                int bh = b * Hc + h;
                float bia = bias[n];
                #pragma unroll
                for (int nt = 0; nt < 4; ++nt) {
                    int l = l0 + wc * 64 + nt * 16 + l16;
                    Vtw[((size_t)bh * Dc + d) * Lc + l] = f2bf(acc[mt][nt][r] + bia);
                }
            }
        }
    }
}

// ---------------------------------------------------------------------------
// Kernel 2: flash attention, rewritten.
//  - 32x32x16 MFMA (S^T = K*Q^T swapped layout; P transpose fully in-register
//    via v_cvt_pk_bf16_f32 + v_permlane32_swap_b32 — no P LDS round-trip)
//  - K/V staged by global_load_lds width=16 into linear [64][64] tiles,
//    XOR-swizzled (slot ^ (row&7)) via pre-swizzled *global* source (both-sides
//    rule), double-buffered, ONE barrier per 64-key tile.
//  - XCD-bijective block swizzle: all 16 q-blocks of one (bh,split) group land
//    on one XCD -> 256KB K/V panel is L2-resident (8 groups x 256KB < 4MB L2).
// ---------------------------------------------------------------------------
__global__ __launch_bounds__(256, 4) void attn_mfma_kernel(
    const unsigned short* __restrict__ Qg,    // [bh][l][64], pre-scaled by 0.125*log2e
    const unsigned short* __restrict__ Kg,    // [bh][l][64]
    const unsigned short* __restrict__ Vtg,   // [bh][64][l]
    unsigned short* __restrict__ O0,          // [b][l][512] bf16 partials
    unsigned short* __restrict__ O1,
    float* __restrict__ lpart)                // [2][bh][l]
{
    // ---- XCD-aware decode: 1024 blocks, group g=(bh*2+split) pinned to XCD g%8
    const int bid = blockIdx.x;
    const int r8  = bid & 7;
    const int j   = bid >> 3;
    const int g   = (j >> 4) * 8 + r8;     // 0..63
    const int x   = j & 15;                // q-block within group
    const int bh    = g >> 1;
    const int split = g & 1;
    const int q0    = x * 128;

    const int tid  = threadIdx.x;
    const int wave = tid >> 6;
    const int lane = tid & 63;
    const int l32  = lane & 31;
    const int hi   = lane >> 5;

    __shared__ __align__(16) unsigned short Kt[2][64 * 64];  // [key][d], swizzled
    __shared__ __align__(16) unsigned short Vt[2][64 * 64];  // [d][key], swizzled

    const unsigned short* Kb = Kg  + (size_t)bh * Lc * Dc;
    const unsigned short* Vb = Vtg + (size_t)bh * Dc * Lc;
    const int kbase = split * (Lc / 2);

    // ---- Q fragments straight from global (B-operand: col q=l32, k=hi*8+e)
    short8 qf[4];
    const unsigned short* Qb =
        Qg + ((size_t)bh * Lc + q0 + wave * 32 + l32) * Dc + hi * 8;
    #pragma unroll
    for (int st = 0; st < 4; ++st)
        qf[st] = *(const short8*)(Qb + st * 16);

    // ---- staging: wave w covers rows [w*16, w*16+16), 2 x 1KB gll per array.
    // LDS[row][slot] holds row-major element slot^(row&7)  (pre-swizzled src).
    const int lrow8 = lane >> 3;        // 0..7 within a 1KB chunk
    const int lslot = lane & 7;
    auto STAGE = [&](int buf, int kc) {
        #pragma unroll
        for (int i = 0; i < 2; ++i) {
            const int r = wave * 16 + i * 8 + lrow8;      // tile row (key / d)
            const int sw = (lslot ^ (r & 7)) * 8;         // ushort offset in row
            gll16(Kb + (size_t)(kbase + kc + r) * Dc + sw,
                  &Kt[buf][(wave * 16 + i * 8) * 64]);
            gll16(Vb + (size_t)r * Lc + (kbase + kc) + sw,
                  &Vt[buf][(wave * 16 + i * 8) * 64]);
        }
    };

    STAGE(0, 0);
    __syncthreads();           // implicit vmcnt(0) drain

    f32x16 O[2] = {};          // [dt]; lane holds O[q=(e&3)+8*(e>>2)+4*hi][dt*32+l32]
    float lsum = 0.0f;

    constexpr int NT = (Lc / 2) / 64;   // 16
    for (int it = 0; it < NT; ++it) {
        const int cur = it & 1;
        if (it + 1 < NT) STAGE(cur ^ 1, (it + 1) * 64);

        // ---- S^T = K·Q^T : 2 key-tiles of 32, k=d accumulated over 4 steps
        f32x16 S0, S1;
        #pragma unroll
        for (int e = 0; e < 16; ++e) { S0[e] = 0.0f; S1[e] = 0.0f; }
        #pragma unroll
        for (int st = 0; st < 4; ++st) {
            const int slot = st * 2 + hi;
            short8 k0 = *(const short8*)
                &Kt[cur][l32 * 64 + ((slot ^ (l32 & 7)) * 8)];
            short8 k1 = *(const short8*)
                &Kt[cur][(32 + l32) * 64 + ((slot ^ (l32 & 7)) * 8)];
            S0 = __builtin_amdgcn_mfma_f32_32x32x16_bf16(k0, qf[st], S0, 0, 0, 0);
            S1 = __builtin_amdgcn_mfma_f32_32x32x16_bf16(k1, qf[st], S1, 0, 0, 0);
        }

        // ---- per 32-key tile: exp2 -> in-register transpose -> PV
        #pragma unroll
        for (int kt = 0; kt < 2; ++kt) {
            const f32x16& S = kt ? S1 : S0;
            float p[16];
            #pragma unroll
            for (int e = 0; e < 16; ++e)
                p[e] = __builtin_amdgcn_exp2f(S[e]);
            #pragma unroll
            for (int e = 0; e < 16; e += 4)
                lsum += (p[e] + p[e + 1]) + (p[e + 2] + p[e + 3]);

            // c[R][w'] = bf16pack(p[4R+2w'], p[4R+2w'+1])
            unsigned int c[4][2];
            #pragma unroll
            for (int R = 0; R < 4; ++R) {
                #pragma unroll
                for (int w = 0; w < 2; ++w)
                    asm("v_cvt_pk_bf16_f32 %0, %1, %2"
                        : "=v"(c[R][w])
                        : "v"(p[4 * R + 2 * w]), "v"(p[4 * R + 2 * w + 1]));
            }

            // A-frag for PV (k=16 per MFMA): word w = c[ksl*2+hi][w&1] from half w>>1
            #pragma unroll
            for (int ksl = 0; ksl < 2; ++ksl) {
                unsigned int a0 = c[2 * ksl][0],     a1 = c[2 * ksl][1];
                unsigned int a2 = c[2 * ksl + 1][0], a3 = c[2 * ksl + 1][1];
                asm("v_permlane32_swap_b32 %0, %1" : "+v"(a0), "+v"(a2));
                asm("v_permlane32_swap_b32 %0, %1" : "+v"(a1), "+v"(a3));
                union { unsigned int w[4]; short8 s; } u;
                u.w[0] = a0; u.w[1] = a1; u.w[2] = a2; u.w[3] = a3;

                const int ksg = kt * 2 + ksl;         // 16-key chunk in 64-tile
                #pragma unroll
                for (int dt = 0; dt < 2; ++dt) {
                    const int row = dt * 32 + l32;    // d row in Vt
                    short8 vf = *(const short8*)
                        &Vt[cur][row * 64 + ((((ksg * 2) + hi) ^ (row & 7)) * 8)];
                    O[dt] = __builtin_amdgcn_mfma_f32_32x32x16_bf16(
                        u.s, vf, O[dt], 0, 0, 0);
                }
            }
        }
        if (it + 1 < NT) __syncthreads();   // drains vmcnt(0): next buffer ready
    }

    // ---- epilogue: partial l + partial O (bf16) ----
    lsum += __shfl_xor(lsum, 32, 64);       // combine hi/lo key-row halves
    const int b = bh >> 3, h = bh & 7;
    unsigned short* Om = split ? O1 : O0;
    float* lp = lpart + (size_t)split * (Bc * Hc) * Lc + (size_t)bh * Lc;
    if (hi == 0)
        lp[q0 + wave * 32 + l32] = lsum;

    #pragma unroll
    for (int dt = 0; dt < 2; ++dt) {
        #pragma unroll
        for (int e = 0; e < 16; ++e) {
            const int q = q0 + wave * 32 + (e & 3) + 8 * (e >> 2) + 4 * hi;
            Om[((size_t)b * Lc + q) * Cc + h * Dc + dt * 32 + l32] =
                f2bf(O[dt][e]);
        }
    }
}

// ---------------------------------------------------------------------------
// Kernel 3: output projection with fused split-K combine (unchanged).
// ---------------------------------------------------------------------------
__global__ __launch_bounds__(256) void outproj_kernel(
    const unsigned short* __restrict__ O0, const unsigned short* __restrict__ O1,
    const float* __restrict__ lpart,
    const unsigned short* __restrict__ Wo_bf,
    const float* __restrict__ bo, const float* __restrict__ ppg,
    float* __restrict__ out)
{
    constexpr int LDW = 72;
    const int b = blockIdx.z;
    const int l0 = blockIdx.x * 128, n0 = blockIdx.y * 128;
    const int tid = threadIdx.x, wave = tid >> 6, lane = tid & 63;
    const int l16 = lane & 15, quad = lane >> 4;
    const int wr = wave >> 1, wc = wave & 1;

    __shared__ __align__(16) unsigned short At[128 * LDW];  // Wo tile [n][c]
    __shared__ __align__(16) unsigned short Bt[128 * LDW];  // ctx tile [l][c]

    float4v acc[4][4] = {};                  // [mt(n)][nt(l)]
    const int srow = tid >> 3, sc8 = tid & 7;
    const size_t lplane = (size_t)(Bc * Hc) * Lc;

    for (int c0 = 0; c0 < Cc; c0 += 64) {
        const int h = c0 >> 6;
        const float* lp0 = lpart + (size_t)(b * Hc + h) * Lc;
        const float* lp1 = lp0 + lplane;

        #pragma unroll
        for (int j = 0; j < 4; ++j) {
            int row = srow + j * 32;
            *(short8*)&At[row * LDW + sc8 * 8] =
                *(const short8*)(Wo_bf + (size_t)(n0 + row) * Cc + c0 + sc8 * 8);
            int l = l0 + row;
            float inv = 1.0f / (lp0[l] + lp1[l]);
            size_t off = ((size_t)b * Lc + l) * Cc + c0 + sc8 * 8;
            short8 a8 = *(const short8*)(O0 + off);
            short8 b8 = *(const short8*)(O1 + off);
            unsigned short pk[8];
            #pragma unroll
            for (int e = 0; e < 8; ++e) {
                unsigned short ua = ((const unsigned short*)&a8)[e];
                unsigned short ub = ((const unsigned short*)&b8)[e];
                pk[e] = f2bf((bf2f(ua) + bf2f(ub)) * inv);
            }
            *(short8*)&Bt[row * LDW + sc8 * 8] = *(const short8*)pk;
        }
        __syncthreads();

        #pragma unroll
        for (int ks = 0; ks < 2; ++ks) {
            short8 bfr[4];
            #pragma unroll
            for (int nt = 0; nt < 4; ++nt)
                bfr[nt] = *(const short8*)&Bt[(wc * 64 + nt * 16 + l16) * LDW
                                              + ks * 32 + quad * 8];
            #pragma unroll
            for (int mt = 0; mt < 4; ++mt) {
                short8 af = *(const short8*)&At[(wr * 64 + mt * 16 + l16) * LDW
                                                + ks * 32 + quad * 8];
                #pragma unroll
                for (int nt = 0; nt < 4; ++nt)
                    acc[mt][nt] = __builtin_amdgcn_mfma_f32_16x16x32_bf16(
                        af, bfr[nt], acc[mt][nt], 0, 0, 0);
            }
        }
        __syncthreads();
    }

    #pragma unroll
    for (int mt = 0; mt < 4; ++mt) {
        #pragma unroll
        for (int r = 0; r < 4; ++r) {
            int n = n0 + wr * 64 + mt * 16 + quad * 4 + r;
            float bia = bo[n];
            #pragma unroll
            for (int nt = 0; nt < 4; ++nt) {
                int l = l0 + wc * 64 + nt * 16 + l16;
                size_t oidx = ((size_t)b * Cc + n) * Lc + l;
                out[oidx] = acc[mt][nt][r] + bia + ppg[oidx];
            }
        }
    }
}

// ---------------------------------------------------------------------------
extern "C" void kernel_launch(void* const* d_in, const int* in_sizes, int n_in,
                              void* d_out, int out_size, void* d_ws, size_t ws_size,
                              hipStream_t stream) {
    const float* ppg = (const float*)d_in[0];
    const float* ecg = (const float*)d_in[1];
    const float* Wq  = (const float*)d_in[2];
    const float* bq  = (const float*)d_in[3];
    const float* Wk  = (const float*)d_in[4];
    const float* bk  = (const float*)d_in[5];
    const float* Wv  = (const float*)d_in[6];
    const float* bv  = (const float*)d_in[7];
    const float* Wo  = (const float*)d_in[8];
    const float* bo  = (const float*)d_in[9];
    float* out = (float*)d_out;

    // Workspace (ushort units), lifetime-based overlays:
    //   [0, 4M)    Xt_ppg   | later Opart0 (bf16 [b][l][c])
    //   [4M, 8M)   Xt_ecg   | later Opart1 (bf16)
    //   [8M, 9M)   Wbf
    //   [9M, 13M)  Qw
    //   [13M, 17M) Kw
    //   [17M, 21M) Vtw
    //   [21M, +512KB) lpart (fp32 [2][bh][l])
    unsigned short* base   = (unsigned short*)d_ws;
    const size_t M = 1024 * 1024;
    unsigned short* Xt_ppg = base;
    unsigned short* Xt_ecg = base + 4 * M;
    unsigned short* Wbf    = base + 8 * M;
    unsigned short* Qw     = base + 9 * M;
    unsigned short* Kw     = base + 13 * M;
    unsigned short* Vtw    = base + 17 * M;
    float* lpart = (float*)(base + 21 * M);
    unsigned short* Opart0 = base;             // overlays Xt_ppg (dead after proj)
    unsigned short* Opart1 = base + 4 * M;     // overlays Xt_ecg (dead after proj)

    prep_kernel<<<2560, 256, 0, stream>>>(ppg, ecg, Wq, Wk, Wv, Wo,
                                          Xt_ppg, Xt_ecg, Wbf);

    dim3 g1(Lc / 128, Cc / 128, 3 * Bc);
    proj_kernel<<<g1, 256, 0, stream>>>(Xt_ppg, Xt_ecg, Wbf, bq, bk, bv,
                                        Qw, Kw, Vtw);

    attn_mfma_kernel<<<1024, 256, 0, stream>>>(Qw, Kw, Vtw, Opart0, Opart1, lpart);

    dim3 g3(Lc / 128, Cc / 128, Bc);
    outproj_kernel<<<g3, 256, 0, stream>>>(Opart0, Opart1, lpart,
                                           Wbf + (size_t)3 * Cc * Cc,
                                           bo, ppg, out);
}